// Round 4
// baseline (169.065 us; speedup 1.0000x reference)
//
#include <hip/hip_runtime.h>

// Problem constants. Harness promotes float16 tensors to float32 on device:
// x, scales, out are all f32; weight_packed is int32 (one packed byte each).
#define M 32
#define N 11008
#define K 4096
#define NGROUPS 32
#define BN 16    // n-rows per block
#define KW 1024  // k per wave (4 waves x 1024 = K)

typedef _Float16 half8 __attribute__((ext_vector_type(8))); // 4 VGPRs
typedef float floatx4 __attribute__((ext_vector_type(4)));

__global__ __launch_bounds__(256) void int4_gemm_kernel(
    const float* __restrict__ x,      // [M][K] f32
    const int* __restrict__ wp,       // [N][K/2] int32, 2 nibbles each
    const float* __restrict__ scales, // [N][NGROUPS] f32
    float* __restrict__ out)          // [M][N] f32
{
    __shared__ float red[4 * M * BN]; // 8 KB: per-wave 32x16 fp32 partials

    const int t    = threadIdx.x;
    const int lane = t & 63;
    const int w    = t >> 6;           // wave id = k-split index
    const int n0   = blockIdx.x * BN;
    const int row  = lane & 15;        // n-row of B fragment / m-row of A fragment
    const int quad = lane >> 4;        // k-subgroup within fragment

    // Per-lane base pointers
    const int* wrow     = wp + (long)(n0 + row) * (K / 2) + (w * (KW / 2)) + quad * 4;
    const float* srow   = scales + (n0 + row) * NGROUPS + w * (KW / 128);
    const float* xr0    = x + row * K + w * KW + quad * 8;
    const float* xr1    = xr0 + 16 * K;

    floatx4 acc0 = {0.f, 0.f, 0.f, 0.f};
    floatx4 acc1 = {0.f, 0.f, 0.f, 0.f};

    #pragma unroll 2
    for (int g = 0; g < KW / 128; ++g) {   // 8 scale-groups of 128 k
        const float s = srow[g];
        floatx4 t0 = {0.f, 0.f, 0.f, 0.f};
        floatx4 t1 = {0.f, 0.f, 0.f, 0.f};
        #pragma unroll
        for (int kk = 0; kk < 4; ++kk) {   // 4 MFMA k-steps of 32
            const int koff = g * 128 + kk * 32; // within-wave k offset
            // B: 8 consecutive k of this lane's n-row = 4 aligned int32
            int4 b4 = *(const int4*)(wrow + (koff >> 1));
            int arr[4] = {b4.x, b4.y, b4.z, b4.w};
            half8 bfrag;
            #pragma unroll
            for (int j = 0; j < 4; ++j) {
                bfrag[2 * j]     = (_Float16)((arr[j] & 15) - 8);        // exact in f16
                bfrag[2 * j + 1] = (_Float16)(((arr[j] >> 4) & 15) - 8); // exact in f16
            }
            // A: 8 consecutive k of m-rows (lane&15) and (lane&15)+16, f32 -> f16
            float4 u0 = *(const float4*)(xr0 + koff);
            float4 u1 = *(const float4*)(xr0 + koff + 4);
            float4 v0 = *(const float4*)(xr1 + koff);
            float4 v1 = *(const float4*)(xr1 + koff + 4);
            half8 a0, a1;
            a0[0] = (_Float16)u0.x; a0[1] = (_Float16)u0.y;
            a0[2] = (_Float16)u0.z; a0[3] = (_Float16)u0.w;
            a0[4] = (_Float16)u1.x; a0[5] = (_Float16)u1.y;
            a0[6] = (_Float16)u1.z; a0[7] = (_Float16)u1.w;
            a1[0] = (_Float16)v0.x; a1[1] = (_Float16)v0.y;
            a1[2] = (_Float16)v0.z; a1[3] = (_Float16)v0.w;
            a1[4] = (_Float16)v1.x; a1[5] = (_Float16)v1.y;
            a1[6] = (_Float16)v1.z; a1[7] = (_Float16)v1.w;

            t0 = __builtin_amdgcn_mfma_f32_16x16x32_f16(a0, bfrag, t0, 0, 0, 0);
            t1 = __builtin_amdgcn_mfma_f32_16x16x32_f16(a1, bfrag, t1, 0, 0, 0);
        }
        #pragma unroll
        for (int r = 0; r < 4; ++r) {
            acc0[r] += s * t0[r];   // fp32 scale application, matches reference
            acc1[r] += s * t1[r];
        }
    }

    // C/D layout: col(n) = lane&15, row(m) = quad*4 + r
    #pragma unroll
    for (int r = 0; r < 4; ++r) {
        red[w * (M * BN) + (quad * 4 + r) * BN + row]      = acc0[r];
        red[w * (M * BN) + (quad * 4 + r + 16) * BN + row] = acc1[r];
    }
    __syncthreads();

    // 512 outputs per block, 2 per thread: sum the 4 per-wave k-partials
    #pragma unroll
    for (int i = 0; i < 2; ++i) {
        int o = t + 256 * i;            // o = m*16 + n
        float sum = red[o] + red[M * BN + o] + red[2 * M * BN + o] + red[3 * M * BN + o];
        int m = o >> 4;
        int n = o & 15;
        out[m * N + n0 + n] = sum;
    }
}

extern "C" void kernel_launch(void* const* d_in, const int* in_sizes, int n_in,
                              void* d_out, int out_size, void* d_ws, size_t ws_size,
                              hipStream_t stream) {
    const float* x      = (const float*)d_in[0];
    const int* wp       = (const int*)d_in[1];
    const float* scales = (const float*)d_in[2];
    float* out          = (float*)d_out;

    int4_gemm_kernel<<<dim3(N / BN), 256, 0, stream>>>(x, wp, scales, out);
}

// Round 5
// 158.821 us; speedup vs baseline: 1.0645x; 1.0645x over previous
//
#include <hip/hip_runtime.h>

// Harness promotes float16 tensors to float32: x, scales, out are f32;
// weight_packed is int32 (one packed byte = 2 nibbles each).
#define M 32
#define N 11008
#define K 4096
#define NGROUPS 32
#define BN 16      // n-rows per block
#define WAVES 8
#define KW 512     // k per wave (8 waves x 512 = K)

typedef _Float16 half8 __attribute__((ext_vector_type(8))); // 4 VGPRs
typedef _Float16 half4 __attribute__((ext_vector_type(4)));
typedef float floatx4 __attribute__((ext_vector_type(4)));

// ---- pre-pass: x f32 -> f16 (512 KB -> 256 KB in d_ws) ----
__global__ __launch_bounds__(512) void xcvt_kernel(
    const float* __restrict__ x, _Float16* __restrict__ xf)
{
    int i = (blockIdx.x * 512 + threadIdx.x) * 4; // M*K = 131072 = 64*512*4
    float4 v = *(const float4*)(x + i);
    half4 h;
    h[0] = (_Float16)v.x; h[1] = (_Float16)v.y;
    h[2] = (_Float16)v.z; h[3] = (_Float16)v.w;
    *(half4*)(xf + i) = h;
}

__global__ __launch_bounds__(512, 6) void int4_gemm_kernel(
    const _Float16* __restrict__ x,   // [M][K] f16 (pre-converted)
    const int* __restrict__ wp,       // [N][K/2] int32, 2 nibbles each
    const float* __restrict__ scales, // [N][NGROUPS] f32
    float* __restrict__ out)          // [M][N] f32
{
    __shared__ float red[WAVES * M * BN]; // 16 KB

    const int t    = threadIdx.x;
    const int lane = t & 63;
    const int w    = t >> 6;           // wave id = k-split index (8-way)
    const int n0   = blockIdx.x * BN;
    const int row  = lane & 15;        // n-row of B / m-row of A
    const int quad = lane >> 4;        // k-subgroup within fragment

    const int* wrow        = wp + (long)(n0 + row) * (K / 2) + w * (KW / 2) + quad * 4;
    const float* srow      = scales + (n0 + row) * NGROUPS + w * (KW / 128);
    const _Float16* xr0    = x + row * K + w * KW + quad * 8;
    const _Float16* xr1    = xr0 + 16 * K;

    floatx4 acc0 = {0.f, 0.f, 0.f, 0.f};
    floatx4 acc1 = {0.f, 0.f, 0.f, 0.f};

    #pragma unroll
    for (int g = 0; g < KW / 128; ++g) {   // 4 scale-groups of 128 k
        const float s = srow[g];
        floatx4 t0 = {0.f, 0.f, 0.f, 0.f};
        floatx4 t1 = {0.f, 0.f, 0.f, 0.f};
        #pragma unroll
        for (int kk = 0; kk < 4; ++kk) {   // 4 MFMA k-steps of 32
            const int koff = g * 128 + kk * 32;
            // B: 8 consecutive k of this lane's n-row = 4 aligned int32
            int4 b4 = *(const int4*)(wrow + (koff >> 1));
            int arr[4] = {b4.x, b4.y, b4.z, b4.w};
            half8 bfrag;
            #pragma unroll
            for (int j = 0; j < 4; ++j) {
                bfrag[2 * j]     = (_Float16)((arr[j] & 15) - 8);        // exact in f16
                bfrag[2 * j + 1] = (_Float16)(((arr[j] >> 4) & 15) - 8); // exact in f16
            }
            half8 a0 = *(const half8*)(xr0 + koff);
            half8 a1 = *(const half8*)(xr1 + koff);
            t0 = __builtin_amdgcn_mfma_f32_16x16x32_f16(a0, bfrag, t0, 0, 0, 0);
            t1 = __builtin_amdgcn_mfma_f32_16x16x32_f16(a1, bfrag, t1, 0, 0, 0);
        }
        #pragma unroll
        for (int r = 0; r < 4; ++r) {
            acc0[r] += s * t0[r];   // fp32 scale application, matches reference
            acc1[r] += s * t1[r];
        }
    }

    // C/D layout: col(n) = lane&15, row(m) = quad*4 + r
    #pragma unroll
    for (int r = 0; r < 4; ++r) {
        red[w * (M * BN) + (quad * 4 + r) * BN + row]      = acc0[r];
        red[w * (M * BN) + (quad * 4 + r + 16) * BN + row] = acc1[r];
    }
    __syncthreads();

    // 512 outputs per block, 1 per thread: sum the 8 per-wave k-partials
    {
        float sum = 0.f;
        #pragma unroll
        for (int i = 0; i < WAVES; ++i) sum += red[i * (M * BN) + t];
        int m = t >> 4;
        int n = t & 15;
        out[m * N + n0 + n] = sum;
    }
}

extern "C" void kernel_launch(void* const* d_in, const int* in_sizes, int n_in,
                              void* d_out, int out_size, void* d_ws, size_t ws_size,
                              hipStream_t stream) {
    const float* x      = (const float*)d_in[0];
    const int* wp       = (const int*)d_in[1];
    const float* scales = (const float*)d_in[2];
    float* out          = (float*)d_out;
    _Float16* xf16      = (_Float16*)d_ws; // 256 KB

    xcvt_kernel<<<dim3((M * K) / (512 * 4)), 512, 0, stream>>>(x, xf16);
    int4_gemm_kernel<<<dim3(N / BN), 512, 0, stream>>>(xf16, wp, scales, out);
}

// Round 6
// 141.801 us; speedup vs baseline: 1.1923x; 1.1200x over previous
//
#include <hip/hip_runtime.h>

// Harness promotes float16 tensors to float32: x, scales, out are f32;
// weight_packed is int32, one byte (2 nibbles) per element.
#define M 32
#define N 11008
#define K 4096
#define NGROUPS 32
#define BN 16                // n-rows per block
#define KSPLIT 4             // k-split across blocks
#define KRANGE (K / KSPLIT)  // 1024 k per block
#define BK 256               // k per staged chunk
#define NCHUNK (KRANGE / BK) // 4

typedef _Float16 half8 __attribute__((ext_vector_type(8))); // 4 VGPRs
typedef _Float16 half4 __attribute__((ext_vector_type(4)));
typedef float floatx4 __attribute__((ext_vector_type(4)));

// LDS layout: rows stored in PAIRS of 512B with 16B pad per pair (bank-spread,
// and global_load_lds needs lane-contiguous 1KB per instruction = 2 rows).
#define WPAIR 260 // ints per weight row-pair: 2*128 + 4 pad (1040 B)
#define XPAIR 520 // halfs per x row-pair:    2*256 + 8 pad (1040 B)

__device__ inline void gll16(const void* g, void* l) {
    __builtin_amdgcn_global_load_lds(
        (const __attribute__((address_space(1))) unsigned int*)g,
        (__attribute__((address_space(3))) unsigned int*)l, 16, 0, 0);
}

// ---- pre-pass: x f32 -> f16 (512 KB -> 256 KB in d_ws) ----
__global__ __launch_bounds__(512) void xcvt_kernel(
    const float* __restrict__ x, _Float16* __restrict__ xf)
{
    int i = (blockIdx.x * 512 + threadIdx.x) * 4; // M*K = 131072 = 64*512*4
    float4 v = *(const float4*)(x + i);
    half4 h;
    h[0] = (_Float16)v.x; h[1] = (_Float16)v.y;
    h[2] = (_Float16)v.z; h[3] = (_Float16)v.w;
    *(half4*)(xf + i) = h;
}

__global__ __launch_bounds__(256) void int4_gemm_kernel(
    const _Float16* __restrict__ xf,  // [M][K] f16 (pre-converted)
    const int* __restrict__ wp,       // [N][K/2] int32, 2 nibbles each
    const float* __restrict__ scales, // [N][NGROUPS] f32
    float* __restrict__ out)          // [M][N] f32, pre-zeroed
{
    __shared__ int wsh[8 * WPAIR];        // 16 w-rows:  8.3 KB
    __shared__ _Float16 xs[16 * XPAIR];   // 32 x-rows: 16.6 KB

    const int t    = threadIdx.x;
    const int lane = t & 63;
    const int w    = t >> 6;        // wave id: splits chunk k 4-ways
    const int n0   = blockIdx.x * BN;
    const int ks   = blockIdx.y;    // k-split index
    const int row  = lane & 15;     // n-row of B / m-row of A fragments
    const int quad = lane >> 4;

    floatx4 acc0 = {0.f, 0.f, 0.f, 0.f};
    floatx4 acc1 = {0.f, 0.f, 0.f, 0.f};

    const half8 c1032 = (half8)(_Float16)1032.0f; // 0x6408, exact

    for (int c = 0; c < NCHUNK; ++c) {
        const int kc = ks * KRANGE + c * BK; // global chunk k-base

        // ---- stage weights: 8 pairs x 1KB, 2 per wave, lane-contiguous ----
        #pragma unroll
        for (int i = 0; i < 2; ++i) {
            int p = w * 2 + i;                // pair 0..7
            int r = 2 * p + (lane >> 5);      // row this lane serves
            const int* g = wp + (long)(n0 + r) * (K / 2) + (kc >> 1) + (lane & 31) * 4;
            gll16(g, &wsh[p * WPAIR]);
        }
        // ---- stage x: 16 pairs x 1KB, 4 per wave ----
        #pragma unroll
        for (int i = 0; i < 4; ++i) {
            int p = w * 4 + i;                // pair 0..15
            int m = 2 * p + (lane >> 5);
            const _Float16* g = xf + m * K + kc + (lane & 31) * 8;
            gll16(g, &xs[p * XPAIR]);
        }
        __syncthreads();

        // ---- compute: wave w owns local k [w*64, w*64+64) = 2 MFMA steps ----
        const float s = scales[(n0 + row) * NGROUPS + (kc >> 7) + (w >> 1)];
        floatx4 t0 = {0.f, 0.f, 0.f, 0.f};
        floatx4 t1 = {0.f, 0.f, 0.f, 0.f};
        #pragma unroll
        for (int kk = 0; kk < 2; ++kk) {
            const int kl = w * 64 + kk * 32; // chunk-local k
            // B: 4 packed ints = 8 consecutive k of this lane's n-row
            int4 wv = *(const int4*)&wsh[(row >> 1) * WPAIR + (row & 1) * 128 + (kl >> 1) + quad * 4];
            uint4 uw;
            {
                unsigned int b;
                b = (unsigned int)wv.x;
                uw.x = ((b | (b << 12)) & 0x000F000Fu) | 0x64006400u;
                b = (unsigned int)wv.y;
                uw.y = ((b | (b << 12)) & 0x000F000Fu) | 0x64006400u;
                b = (unsigned int)wv.z;
                uw.z = ((b | (b << 12)) & 0x000F000Fu) | 0x64006400u;
                b = (unsigned int)wv.w;
                uw.w = ((b | (b << 12)) & 0x000F000Fu) | 0x64006400u;
            }
            half8 bfrag = __builtin_bit_cast(half8, uw) - c1032; // exact (nib-8)

            int x0 = (row >> 1) * XPAIR + (row & 1) * 256 + kl + quad * 8;
            half8 a0 = *(const half8*)&xs[x0];
            half8 a1 = *(const half8*)&xs[x0 + 8 * XPAIR]; // m-row + 16
            t0 = __builtin_amdgcn_mfma_f32_16x16x32_f16(a0, bfrag, t0, 0, 0, 0);
            t1 = __builtin_amdgcn_mfma_f32_16x16x32_f16(a1, bfrag, t1, 0, 0, 0);
        }
        #pragma unroll
        for (int r = 0; r < 4; ++r) {
            acc0[r] += s * t0[r]; // fp32 scale application, matches reference
            acc1[r] += s * t1[r];
        }
        __syncthreads();
    }

    // ---- epilogue: reduce 4 waves' k-partials in LDS, one atomic per out ----
    float* red = (float*)xs; // 8 KB, xs no longer needed
    #pragma unroll
    for (int r = 0; r < 4; ++r) {
        // C/D layout: col(n) = lane&15, row(m) = quad*4 + r
        red[w * 512 + (quad * 4 + r) * 16 + row]      = acc0[r];
        red[w * 512 + (quad * 4 + r + 16) * 16 + row] = acc1[r];
    }
    __syncthreads();
    #pragma unroll
    for (int i = 0; i < 2; ++i) {
        int o = t + 256 * i; // o = m*16 + n
        float sum = red[o] + red[512 + o] + red[1024 + o] + red[1536 + o];
        int m = o >> 4;
        int n = o & 15;
        atomicAdd(&out[m * N + n0 + n], sum);
    }
}

extern "C" void kernel_launch(void* const* d_in, const int* in_sizes, int n_in,
                              void* d_out, int out_size, void* d_ws, size_t ws_size,
                              hipStream_t stream) {
    const float* x      = (const float*)d_in[0];
    const int* wp       = (const int*)d_in[1];
    const float* scales = (const float*)d_in[2];
    float* out          = (float*)d_out;
    _Float16* xf16      = (_Float16*)d_ws; // 256 KB

    hipMemsetAsync(out, 0, (size_t)M * N * sizeof(float), stream);
    xcvt_kernel<<<dim3((M * K) / (512 * 4)), 512, 0, stream>>>(x, xf16);
    int4_gemm_kernel<<<dim3(N / BN, KSPLIT), 256, 0, stream>>>(xf16, wp, scales, out);
}